// Round 7
// baseline (150.295 us; speedup 1.0000x reference)
//
#include <hip/hip_runtime.h>
#include <hip/hip_bf16.h>

// out[t,l] = sum_{ijk} p1[t,i] p2[t,j] p3[t,k] grid[i,j,k,l]
// GEMM M=16384, K=4096 (k=i*256+j*16+kk), N=768; A built in registers.
// v6: 3-buffer counted-vmcnt pipeline (never drain to 0 in loop),
//     p1 in f16 LDS, v_pk_fma_f32 in k_pre.

using short8 = __attribute__((ext_vector_type(8))) short;
using f32x2  = __attribute__((ext_vector_type(2))) float;
using f32x4  = __attribute__((ext_vector_type(4))) float;
using f32x16 = __attribute__((ext_vector_type(16))) float;
using half8  = __attribute__((ext_vector_type(8))) _Float16;
using half2v = __attribute__((ext_vector_type(2))) _Float16;
typedef unsigned short ushort_t;
typedef unsigned int uint_t;

typedef const __attribute__((address_space(1))) void* gptr_t;
typedef __attribute__((address_space(3))) void* lptr_t;

#define PSTRIDE 52            // p row stride (floats)

static __device__ __forceinline__ ushort_t f2h_bits(float x) {
  union { _Float16 h; ushort_t u; } c;
  c.h = (_Float16)x;          // RNE
  return c.u;
}

// packed f32x2 -> f16x2 (RTZ), bit-cast to _Float16 vector
static __device__ __forceinline__ half2v cvt_pkrtz2(float a, float b) {
  auto r = __builtin_amdgcn_cvt_pkrtz(a, b);
  union { decltype(r) i; half2v o; } u;
  u.i = r;
  return u.o;
}

// ---------------------------------------------------------------------------
// Fused pre-kernel: blocks 0..767 transpose grid -> gT (f16, [768][4096]);
// blocks 768..1023 compute p[t][48] = softmax16((x@W+b)/temp) (f32).
// ---------------------------------------------------------------------------
__global__ __launch_bounds__(512) void k_pre(const float* __restrict__ g,
                                             ushort_t* __restrict__ gT,
                                             const float* __restrict__ x,
                                             const float* __restrict__ W1, const float* __restrict__ b1,
                                             const float* __restrict__ W2, const float* __restrict__ b2,
                                             const float* __restrict__ W3, const float* __restrict__ b3,
                                             const float* __restrict__ temp,
                                             float* __restrict__ p) {
  __shared__ union SmT {
    ushort_t tile[64][65];                  //  8,320 B (transpose path)
    float x2[2][64][100];                   // 51,200 B (prep path)
    float partial[4][64][PSTRIDE];          // 53,248 B (prep path)
  } sm;
  const int tid = threadIdx.x;
  const int bid = blockIdx.x;

  if (bid < 768) {
    // ---- transpose tile: grid (4096 x 768 f32) -> gT (768 x 4096 f16) ----
    const int r0 = (bid & 63) * 64;         // ijk base
    const int c0 = (bid >> 6) * 64;         // l base
#pragma unroll
    for (int it = 0; it < 2; ++it) {
      const int idx = tid + it * 512;       // 0..1023
      const int r = idx >> 4;
      const int c = (idx & 15) << 2;
      const float4 v = *(const float4*)(g + (size_t)(r0 + r) * 768 + (c0 + c));
      sm.tile[c + 0][r] = f2h_bits(v.x);
      sm.tile[c + 1][r] = f2h_bits(v.y);
      sm.tile[c + 2][r] = f2h_bits(v.z);
      sm.tile[c + 3][r] = f2h_bits(v.w);
    }
    __syncthreads();
#pragma unroll
    for (int it = 0; it < 2; ++it) {
      const int idx = tid + it * 512;
      const int r = idx >> 4;
      const int c = (idx & 15) << 2;
      ushort4 o;
      o.x = sm.tile[r][c + 0]; o.y = sm.tile[r][c + 1];
      o.z = sm.tile[r][c + 2]; o.w = sm.tile[r][c + 3];
      *(ushort4*)(gT + (size_t)(c0 + r) * 4096 + (r0 + c)) = o;
    }
    return;
  }

  // ---- prep block: 64 tokens, x staged in LDS chunks (coalesced) ----
  const int lane = tid & 63;
  const int wv = __builtin_amdgcn_readfirstlane(tid >> 6);  // 0..7 = d-slice
  const int t0 = (bid - 768) * 64;

  float acc[48];
#pragma unroll
  for (int q = 0; q < 48; ++q) acc[q] = 0.f;
  f32x2* a2 = (f32x2*)acc;

  const float* xbase = x + (size_t)t0 * 768;
  auto load_chunk = [&](int c, int b) {
#pragma unroll
    for (int it = 0; it < 3; ++it) {
      const int q = tid + it * 512;         // 0..1535
      const int r = q / 24;
      const int c4 = q % 24;
      const float4 v = *(const float4*)(xbase + (size_t)r * 768 + c * 96 + c4 * 4);
      *(float4*)&sm.x2[b][r][c4 * 4] = v;
    }
  };

  load_chunk(0, 0);
  __syncthreads();
  for (int c = 0; c < 8; ++c) {
    const int cur = c & 1;
    if (c < 7) load_chunk(c + 1, cur ^ 1);
    float xv[12];
#pragma unroll
    for (int rr = 0; rr < 3; ++rr) {
      const f32x4 v = *(const f32x4*)&sm.x2[cur][lane][wv * 12 + rr * 4];
      xv[rr * 4 + 0] = v[0]; xv[rr * 4 + 1] = v[1];
      xv[rr * 4 + 2] = v[2]; xv[rr * 4 + 3] = v[3];
    }
#pragma unroll
    for (int dd = 0; dd < 12; ++dd) {
      const int d = c * 96 + wv * 12 + dd;
      const float xs = xv[dd];
      const f32x2 xs2 = {xs, xs};
      const f32x2* w1r = (const f32x2*)(W1 + d * 16);
      const f32x2* w2r = (const f32x2*)(W2 + d * 16);
      const f32x2* w3r = (const f32x2*)(W3 + d * 16);
#pragma unroll
      for (int gg = 0; gg < 8; ++gg) {
        a2[gg]      = __builtin_elementwise_fma(xs2, w1r[gg], a2[gg]);
        a2[8 + gg]  = __builtin_elementwise_fma(xs2, w2r[gg], a2[8 + gg]);
        a2[16 + gg] = __builtin_elementwise_fma(xs2, w3r[gg], a2[16 + gg]);
      }
    }
    __syncthreads();
  }

  // tree reduce 8 -> 4 -> 2 -> 1
  if (wv >= 4) {
    f32x4* dst = (f32x4*)sm.partial[wv - 4][lane];
#pragma unroll
    for (int q = 0; q < 12; ++q) dst[q] = *(const f32x4*)&acc[q * 4];
  }
  __syncthreads();
  if (wv < 4) {
    const f32x4* src = (const f32x4*)sm.partial[wv][lane];
#pragma unroll
    for (int q = 0; q < 12; ++q) {
      const f32x4 v = src[q];
#pragma unroll
      for (int e = 0; e < 4; ++e) acc[q * 4 + e] += v[e];
    }
  }
  __syncthreads();
  if (wv == 2 || wv == 3) {
    f32x4* dst = (f32x4*)sm.partial[wv - 2][lane];
#pragma unroll
    for (int q = 0; q < 12; ++q) dst[q] = *(const f32x4*)&acc[q * 4];
  }
  __syncthreads();
  if (wv < 2) {
    const f32x4* src = (const f32x4*)sm.partial[wv][lane];
#pragma unroll
    for (int q = 0; q < 12; ++q) {
      const f32x4 v = src[q];
#pragma unroll
      for (int e = 0; e < 4; ++e) acc[q * 4 + e] += v[e];
    }
  }
  __syncthreads();
  if (wv == 1) {
    f32x4* dst = (f32x4*)sm.partial[0][lane];
#pragma unroll
    for (int q = 0; q < 12; ++q) dst[q] = *(const f32x4*)&acc[q * 4];
  }
  __syncthreads();
  if (wv == 0) {
    const f32x4* src = (const f32x4*)sm.partial[0][lane];
#pragma unroll
    for (int q = 0; q < 12; ++q) {
      const f32x4 v = src[q];
#pragma unroll
      for (int e = 0; e < 4; ++e) acc[q * 4 + e] += v[e];
    }
    const float invT = 1.0f / temp[0];
    float* prow = p + (size_t)(t0 + lane) * PSTRIDE;
#pragma unroll
    for (int grp = 0; grp < 3; ++grp) {
      const float* bias = (grp == 0) ? b1 : (grp == 1) ? b2 : b3;
      float z[16];
      float m = -3.0e38f;
#pragma unroll
      for (int q = 0; q < 16; ++q) {
        z[q] = (acc[grp * 16 + q] + bias[q]) * invT;
        m = fmaxf(m, z[q]);
      }
      float s = 0.f;
#pragma unroll
      for (int q = 0; q < 16; ++q) { z[q] = __expf(z[q] - m); s += z[q]; }
      const float rs = 1.0f / s;
#pragma unroll
      for (int q = 0; q < 16; ++q) prow[grp * 16 + q] = z[q] * rs;
    }
  }
}

// ---------------------------------------------------------------------------
// GEMM. BM=128 BN=192 BK=64; 4 waves 2x2, wave tile 64x96,
// v_mfma_f32_32x32x16_f16. 3-buffer pipeline with counted vmcnt:
// iter kt issues stage(kt+2), computes buf kt%3, waits vmcnt(6) (tile kt+1
// done, kt+2 still in flight). Never drains to 0 in the loop.
// ---------------------------------------------------------------------------
__global__ __launch_bounds__(256, 2) void k_gemm(const float* __restrict__ p_g,
                                                 const ushort_t* __restrict__ gT,
                                                 float* __restrict__ out) {
  __shared__ ushort_t Bt[3 * 192 * 64];       // 73,728 B
  __shared__ ushort_t p1h[16 * 128];          //  4,096 B (p1 as f16)

  const int tid = threadIdx.x;
  const int lane = tid & 63;
  const int wv = __builtin_amdgcn_readfirstlane(tid >> 6);
  const int wm = wv >> 1, wn = wv & 1;
  const int g = lane >> 5;                    // k-half 0/1
  const int l31 = lane & 31;

  // XCD-aware swizzle over 512 blocks (512 % 8 == 0 -> bijective)
  const int f = blockIdx.y * 128 + blockIdx.x;
  const int w = (f & 7) * 64 + (f >> 3);
  const int m0 = (w & 127) * 128;
  const int n0 = (w >> 7) * 192;

  // p1h[i][row] cooperative build (f16)
  if (tid < 128) {
    const float* pr = p_g + (size_t)(m0 + tid) * PSTRIDE;
#pragma unroll
    for (int qq = 0; qq < 4; ++qq) {
      const f32x4 v = *(const f32x4*)(pr + qq * 4);
#pragma unroll
      for (int e = 0; e < 4; ++e) p1h[(qq * 4 + e) * 128 + tid] = f2h_bits(v[e]);
    }
  }

  // per-lane p2 (16 f16-broadcast pairs) and p3 (own k-half, 8 f32) per m-rep
  const int rowA0 = m0 + wm * 64 + l31;
  half2v p2h[2][16];
  float p3r[2][8];
#pragma unroll
  for (int mr = 0; mr < 2; ++mr) {
    const float* pr = p_g + (size_t)(rowA0 + mr * 32) * PSTRIDE;
#pragma unroll
    for (int qq = 0; qq < 4; ++qq) {
      const f32x4 v = *(const f32x4*)(pr + 16 + qq * 4);
#pragma unroll
      for (int e = 0; e < 4; ++e)
        p2h[mr][qq * 4 + e] = cvt_pkrtz2(v[e], v[e]);
    }
#pragma unroll
    for (int qq = 0; qq < 2; ++qq) {
      const f32x4 v = *(const f32x4*)(pr + 32 + 8 * g + qq * 4);
      p3r[mr][qq * 4 + 0] = v[0]; p3r[mr][qq * 4 + 1] = v[1];
      p3r[mr][qq * 4 + 2] = v[2]; p3r[mr][qq * 4 + 3] = v[3];
    }
  }

  // B staging: linear LDS dest + inverse-swizzled source (16B chunks)
  const int srow = wv * 48 + (lane >> 3);
  const int schunk = (lane & 7) ^ (lane >> 3);
  const ushort_t* sbase = gT + (size_t)(n0 + srow) * 4096 + schunk * 8;
  auto stage = [&](int buf, int kt) {
    const ushort_t* src = sbase + kt * 64;
#pragma unroll
    for (int q = 0; q < 6; ++q) {
      __builtin_amdgcn_global_load_lds((gptr_t)(src + (size_t)q * 8 * 4096),
                                       (lptr_t)&Bt[buf * 12288 + (wv * 48 + q * 8) * 64], 16, 0, 0);
    }
  };

  f32x16 acc[2][3];
#pragma unroll
  for (int mr = 0; mr < 2; ++mr)
#pragma unroll
    for (int nf = 0; nf < 3; ++nf)
#pragma unroll
      for (int e = 0; e < 16; ++e) acc[mr][nf][e] = 0.f;

  // drain all p-traffic (global reads + LDS writes) before counted staging
  asm volatile("s_waitcnt vmcnt(0) lgkmcnt(0)" ::: "memory");
  __builtin_amdgcn_s_barrier();

  stage(0, 0);
  stage(1, 1);
  asm volatile("s_waitcnt vmcnt(6)" ::: "memory");  // tile 0 landed
  __builtin_amdgcn_s_barrier();

  const int rowLoc0 = wm * 64 + l31;
  int bufc = 0;                               // compute buffer (kt%3)
  int sbuf = 2;                               // stage target ((kt+2)%3)
  for (int io = 0; io < 16; ++io) {           // i-index (p1)
    half2v p1p3h[2][4];
#pragma unroll
    for (int mr = 0; mr < 2; ++mr) {
      union { ushort_t u; _Float16 h; } c;
      c.u = p1h[io * 128 + rowLoc0 + mr * 32];
      const float p1v = (float)c.h;
#pragma unroll
      for (int q = 0; q < 4; ++q)
        p1p3h[mr][q] = cvt_pkrtz2(p1v * p3r[mr][2 * q],
                                  p1v * p3r[mr][2 * q + 1]);
    }
#pragma unroll
    for (int kq = 0; kq < 4; ++kq) {
      const int kt = io * 4 + kq;
      // prefetch tile kt+2 (counted, stays in flight across this compute)
      if (kt < 62) stage(sbuf, kt + 2);

      const ushort_t* bbuf = &Bt[bufc * 12288];
      half8 b[4][3];
#pragma unroll
      for (int s = 0; s < 4; ++s) {
        const int cd = 2 * s + g;
#pragma unroll
        for (int nf = 0; nf < 3; ++nf) {
          const int r = wn * 96 + nf * 32 + l31;
          b[s][nf] = *(const half8*)&bbuf[r * 64 + ((cd ^ (r & 7)) << 3)];
        }
      }

#pragma unroll
      for (int s = 0; s < 4; ++s) {
        const int j = kq * 4 + s;             // static p2 index
        half8 a[2];
#pragma unroll
        for (int mr = 0; mr < 2; ++mr) {
          union { half2v h2[4]; half8 h8; } pk;
#pragma unroll
          for (int q = 0; q < 4; ++q) pk.h2[q] = p2h[mr][j] * p1p3h[mr][q];
          a[mr] = pk.h8;
        }
        __builtin_amdgcn_s_setprio(1);
#pragma unroll
        for (int mr = 0; mr < 2; ++mr)
#pragma unroll
          for (int nf = 0; nf < 3; ++nf)
            acc[mr][nf] = __builtin_amdgcn_mfma_f32_32x32x16_f16(a[mr], b[s][nf], acc[mr][nf], 0, 0, 0);
        __builtin_amdgcn_s_setprio(0);
      }

      // end of iter: ensure NEXT tile (kt+1) is resident; keep kt+2 flying
      if (kt < 62) {
        asm volatile("s_waitcnt vmcnt(6)" ::: "memory");
      } else if (kt == 62) {
        asm volatile("s_waitcnt vmcnt(0)" ::: "memory");
      }
      if (kt < 63) __builtin_amdgcn_s_barrier();
      bufc = (bufc == 2) ? 0 : bufc + 1;
      sbuf = (sbuf == 2) ? 0 : sbuf + 1;
    }
  }

  // epilogue: 32x32 C/D: col = lane&31, row = (reg&3)+8*(reg>>2)+4*(lane>>5)
#pragma unroll
  for (int mr = 0; mr < 2; ++mr)
#pragma unroll
    for (int nf = 0; nf < 3; ++nf)
#pragma unroll
      for (int reg = 0; reg < 16; ++reg) {
        const int row = (reg & 3) + 8 * (reg >> 2) + 4 * g;
        const int t = m0 + wm * 64 + mr * 32 + row;
        out[(size_t)t * 768 + n0 + wn * 96 + nf * 32 + l31] = acc[mr][nf][reg];
      }
}

// ---------------------------------------------------------------------------
extern "C" void kernel_launch(void* const* d_in, const int* in_sizes, int n_in,
                              void* d_out, int out_size, void* d_ws, size_t ws_size,
                              hipStream_t stream) {
  (void)in_sizes; (void)n_in; (void)out_size; (void)ws_size;
  const float* x    = (const float*)d_in[0];
  const float* W1   = (const float*)d_in[1];
  const float* b1   = (const float*)d_in[2];
  const float* W2   = (const float*)d_in[3];
  const float* b2   = (const float*)d_in[4];
  const float* W3   = (const float*)d_in[5];
  const float* b3   = (const float*)d_in[6];
  const float* grid = (const float*)d_in[7];
  const float* temp = (const float*)d_in[8];
  float* out = (float*)d_out;

  // ws: gT f16 [768][4096] = 6,291,456 B ; p f32 [16384][52] = 3,407,872 B
  ushort_t* gT = (ushort_t*)d_ws;
  float* p = (float*)((char*)d_ws + 6291456);

  k_pre<<<dim3(1024), 512, 0, stream>>>(grid, gT, x, W1, b1, W2, b2, W3, b3, temp, p);
  k_gemm<<<dim3(128, 4), 256, 0, stream>>>(p, gT, out);
}